// Round 1
// baseline (1496.453 us; speedup 1.0000x reference)
//
#include <hip/hip_runtime.h>

#define NN 50000
#define NE 800000
#define NG 128
#define OUTC 10

// ---------------------------------------------------------------- CSR build
__global__ void count_kernel(const int* __restrict__ dst, int* __restrict__ cnt) {
  for (int e = blockIdx.x * blockDim.x + threadIdx.x; e < NE; e += gridDim.x * blockDim.x)
    atomicAdd(&cnt[dst[e]], 1);
}

__global__ __launch_bounds__(1024) void scan_kernel(const int* __restrict__ cnt,
                                                    int* __restrict__ rowptr,
                                                    int* __restrict__ cursor) {
  __shared__ int part[1024];
  const int t = threadIdx.x;
  const int CH = (NN + 1023) / 1024;  // 49
  const int base = t * CH;
  int s = 0;
  for (int i = 0; i < CH; ++i) { int idx = base + i; if (idx < NN) s += cnt[idx]; }
  part[t] = s;
  __syncthreads();
  for (int off = 1; off < 1024; off <<= 1) {
    int v = (t >= off) ? part[t - off] : 0;
    __syncthreads();
    part[t] += v;
    __syncthreads();
  }
  int run = (t == 0) ? 0 : part[t - 1];
  for (int i = 0; i < CH; ++i) {
    int idx = base + i;
    if (idx < NN) { rowptr[idx] = run; cursor[idx] = run; run += cnt[idx]; }
  }
  if (t == 1023) rowptr[NN] = part[1023];
}

__global__ void fill_kernel(const int* __restrict__ src, const int* __restrict__ dst,
                            int* __restrict__ cursor, int* __restrict__ esrc) {
  for (int e = blockIdx.x * blockDim.x + threadIdx.x; e < NE; e += gridDim.x * blockDim.x) {
    int p = atomicAdd(&cursor[dst[e]], 1);
    esrc[p] = src[e];
  }
}

// ------------------------------------------------- fused GIN layer + JK chunk
// per wave: one row. z = h[row] + sum_{nbr} h[nbr]  (gather via CSR)
// h1 = relu(z @ W1 + b1); h = relu(h1 @ W2 + b2); hout = h
// hjk (+)= h @ Wjk   (JK 'cat' projection chunk for this layer)
template <int K, bool FIRST>
__global__ __launch_bounds__(256) void gin_layer(
    const float* __restrict__ hin, const int* __restrict__ rowptr,
    const int* __restrict__ esrc,
    const float* __restrict__ w1, const float* __restrict__ b1,
    const float* __restrict__ w2, const float* __restrict__ b2,
    const float* __restrict__ wjk, const float* __restrict__ bjk,
    float* __restrict__ hout, float* __restrict__ hjk) {
  __shared__ float sW1[K * 64];
  __shared__ float sW2[64 * 64];
  __shared__ float sWJ[64 * 64];
  __shared__ float sZ[4][K];
  __shared__ float sH1[4][64];
  __shared__ float sH2[4][64];
  const int t = threadIdx.x, wv = t >> 6, ln = t & 63;
  for (int i = t; i < K * 64; i += 256) sW1[i] = w1[i];
  for (int i = t; i < 64 * 64; i += 256) { sW2[i] = w2[i]; sWJ[i] = wjk[i]; }
  __syncthreads();

  const int stride = gridDim.x * 4;
  const int iters = (NN + stride - 1) / stride;
  for (int it = 0; it < iters; ++it) {
    const int row = (it * gridDim.x + blockIdx.x) * 4 + wv;
    const bool act = row < NN;
    if (act) {
      float z[K / 64];
#pragma unroll
      for (int u = 0; u < K / 64; ++u) z[u] = hin[(size_t)row * K + u * 64 + ln];
      const int beg = rowptr[row], end = rowptr[row + 1];
      for (int e = beg; e < end; ++e) {
        const int s = esrc[e];
        const float* hs = hin + (size_t)s * K;
#pragma unroll
        for (int u = 0; u < K / 64; ++u) z[u] += hs[u * 64 + ln];
      }
#pragma unroll
      for (int u = 0; u < K / 64; ++u) sZ[wv][u * 64 + ln] = z[u];
    }
    __syncthreads();
    if (act) {
      float a0 = b1[ln], a1 = 0.f, a2 = 0.f, a3 = 0.f;
#pragma unroll 4
      for (int k = 0; k < K; k += 4) {
        a0 += sZ[wv][k + 0] * sW1[(k + 0) * 64 + ln];
        a1 += sZ[wv][k + 1] * sW1[(k + 1) * 64 + ln];
        a2 += sZ[wv][k + 2] * sW1[(k + 2) * 64 + ln];
        a3 += sZ[wv][k + 3] * sW1[(k + 3) * 64 + ln];
      }
      sH1[wv][ln] = fmaxf((a0 + a1) + (a2 + a3), 0.f);
    }
    __syncthreads();
    if (act) {
      float a0 = b2[ln], a1 = 0.f, a2 = 0.f, a3 = 0.f;
#pragma unroll 4
      for (int k = 0; k < 64; k += 4) {
        a0 += sH1[wv][k + 0] * sW2[(k + 0) * 64 + ln];
        a1 += sH1[wv][k + 1] * sW2[(k + 1) * 64 + ln];
        a2 += sH1[wv][k + 2] * sW2[(k + 2) * 64 + ln];
        a3 += sH1[wv][k + 3] * sW2[(k + 3) * 64 + ln];
      }
      float h = fmaxf((a0 + a1) + (a2 + a3), 0.f);
      sH2[wv][ln] = h;
      hout[(size_t)row * 64 + ln] = h;
    }
    __syncthreads();
    if (act) {
      float a0 = FIRST ? bjk[ln] : hjk[(size_t)row * 64 + ln];
      float a1 = 0.f, a2 = 0.f, a3 = 0.f;
#pragma unroll 4
      for (int k = 0; k < 64; k += 4) {
        a0 += sH2[wv][k + 0] * sWJ[(k + 0) * 64 + ln];
        a1 += sH2[wv][k + 1] * sWJ[(k + 1) * 64 + ln];
        a2 += sH2[wv][k + 2] * sWJ[(k + 2) * 64 + ln];
        a3 += sH2[wv][k + 3] * sWJ[(k + 3) * 64 + ln];
      }
      hjk[(size_t)row * 64 + ln] = (a0 + a1) + (a2 + a3);
    }
    __syncthreads();
  }
}

// ---------------------------------------------------------------- add-pool
__global__ __launch_bounds__(256) void pool_kernel(const float* __restrict__ hjk,
                                                   const int* __restrict__ batch,
                                                   float* __restrict__ g) {
  __shared__ float sg[NG * 64];
  for (int i = threadIdx.x; i < NG * 64; i += 256) sg[i] = 0.f;
  __syncthreads();
  const int c = threadIdx.x & 63, nw = threadIdx.x >> 6;
  for (int nb = blockIdx.x * 4; nb < NN; nb += gridDim.x * 4) {
    const int node = nb + nw;
    if (node < NN) {
      const int b = batch[node];
      atomicAdd(&sg[b * 64 + c], hjk[(size_t)node * 64 + c]);
    }
  }
  __syncthreads();
  for (int i = threadIdx.x; i < NG * 64; i += 256) atomicAdd(&g[i], sg[i]);
}

// ------------------------------------------------------------- classifier
__global__ __launch_bounds__(256) void classifier_kernel(
    const float* __restrict__ g, const float* __restrict__ w1,
    const float* __restrict__ b1, const float* __restrict__ gamma,
    const float* __restrict__ beta, const float* __restrict__ w2,
    const float* __restrict__ b2, float* __restrict__ out) {
  __shared__ float sT[NG * 64];
  __shared__ float sW1[64 * 64];
  __shared__ float sW2[64 * OUTC];
  __shared__ float sMu[64], sRs[64];
  const int t = threadIdx.x;
  for (int i = t; i < 64 * 64; i += 256) sW1[i] = w1[i];
  for (int i = t; i < 64 * OUTC; i += 256) sW2[i] = w2[i];
  __syncthreads();
  for (int idx = t; idx < NG * 64; idx += 256) {
    const int gi = idx >> 6, c = idx & 63;
    float a = b1[c];
    for (int k = 0; k < 64; ++k) a += g[gi * 64 + k] * sW1[k * 64 + c];
    sT[idx] = a;
  }
  __syncthreads();
  if (t < 64) {
    float s = 0.f;
    for (int gi = 0; gi < NG; ++gi) s += sT[gi * 64 + t];
    const float mu = s / NG;
    float v = 0.f;
    for (int gi = 0; gi < NG; ++gi) { float d = sT[gi * 64 + t] - mu; v += d * d; }
    v /= NG;
    sMu[t] = mu;
    sRs[t] = rsqrtf(v + 1e-5f);
  }
  __syncthreads();
  for (int idx = t; idx < NG * 64; idx += 256) {
    const int c = idx & 63;
    sT[idx] = fmaxf((sT[idx] - sMu[c]) * sRs[c] * gamma[c] + beta[c], 0.f);
  }
  __syncthreads();
  for (int idx = t; idx < NG * OUTC; idx += 256) {
    const int gi = idx / OUTC, o = idx % OUTC;
    float a = b2[o];
    for (int k = 0; k < 64; ++k) a += sT[gi * 64 + k] * sW2[k * OUTC + o];
    out[idx] = a;
  }
}

// ---------------------------------------------------------------- launch
extern "C" void kernel_launch(void* const* d_in, const int* in_sizes, int n_in,
                              void* d_out, int out_size, void* d_ws, size_t ws_size,
                              hipStream_t stream) {
  const float* x     = (const float*)d_in[0];
  const int*   ei    = (const int*)d_in[1];
  const int*   batch = (const int*)d_in[2];
  const float* w1_0  = (const float*)d_in[3];
  const float* b1_0  = (const float*)d_in[4];
  const float* w2_0  = (const float*)d_in[5];
  const float* b2_0  = (const float*)d_in[6];
  const float* w1_r  = (const float*)d_in[7];
  const float* b1_r  = (const float*)d_in[8];
  const float* w2_r  = (const float*)d_in[9];
  const float* b2_r  = (const float*)d_in[10];
  const float* jk_w  = (const float*)d_in[11];
  const float* jk_b  = (const float*)d_in[12];
  const float* cw1   = (const float*)d_in[13];
  const float* cb1   = (const float*)d_in[14];
  const float* bng   = (const float*)d_in[15];
  const float* bnb   = (const float*)d_in[16];
  const float* cw2   = (const float*)d_in[17];
  const float* cb2   = (const float*)d_in[18];
  float* out = (float*)d_out;

  char* base = (char*)d_ws;
  size_t o = 0;
  auto take = [&](size_t n) { char* p = base + o; o = (o + n + 255) & ~(size_t)255; return p; };
  int*   cnt    = (int*)take((size_t)NN * 4);
  int*   rowptr = (int*)take((size_t)(NN + 1) * 4);
  int*   cursor = (int*)take((size_t)NN * 4);
  int*   esrc   = (int*)take((size_t)NE * 4);
  float* hA     = (float*)take((size_t)NN * 64 * 4);
  float* hB     = (float*)take((size_t)NN * 64 * 4);
  float* hjk    = (float*)take((size_t)NN * 64 * 4);
  float* g      = (float*)take((size_t)NG * 64 * 4);
  (void)ws_size; (void)in_sizes; (void)n_in; (void)out_size;

  hipMemsetAsync(cnt, 0, (size_t)NN * 4, stream);
  hipMemsetAsync(g, 0, (size_t)NG * 64 * 4, stream);

  const int* src = ei;
  const int* dst = ei + NE;
  count_kernel<<<1024, 256, 0, stream>>>(dst, cnt);
  scan_kernel<<<1, 1024, 0, stream>>>(cnt, rowptr, cursor);
  fill_kernel<<<1024, 256, 0, stream>>>(src, dst, cursor, esrc);

  // layer 0: IN_CH=128
  gin_layer<128, true><<<512, 256, 0, stream>>>(x, rowptr, esrc, w1_0, b1_0, w2_0,
                                                b2_0, jk_w, jk_b, hA, hjk);
  const float* hin = hA;
  float* hout = hB;
  for (int l = 1; l < 5; ++l) {
    gin_layer<64, false><<<768, 256, 0, stream>>>(
        hin, rowptr, esrc, w1_r + (size_t)(l - 1) * 64 * 64, b1_r + (size_t)(l - 1) * 64,
        w2_r + (size_t)(l - 1) * 64 * 64, b2_r + (size_t)(l - 1) * 64,
        jk_w + (size_t)l * 64 * 64, jk_b, hout, hjk);
    float* tmp = (float*)hin;
    hin = hout;
    hout = tmp;
  }

  pool_kernel<<<128, 256, 0, stream>>>(hjk, batch, g);
  classifier_kernel<<<1, 256, 0, stream>>>(g, cw1, cb1, bng, bnb, cw2, cb2, out);
}

// Round 2
// 716.071 us; speedup vs baseline: 2.0898x; 2.0898x over previous
//
#include <hip/hip_runtime.h>

#define NN 50000
#define NE 800000
#define NG 128
#define OUTC 10

// ---------------------------------------------------------------- CSR build
__global__ void count_kernel(const int* __restrict__ dst, int* __restrict__ cnt) {
  for (int e = blockIdx.x * blockDim.x + threadIdx.x; e < NE; e += gridDim.x * blockDim.x)
    atomicAdd(&cnt[dst[e]], 1);
}

__global__ __launch_bounds__(1024) void scan_kernel(const int* __restrict__ cnt,
                                                    int* __restrict__ rowptr,
                                                    int* __restrict__ cursor) {
  __shared__ int part[1024];
  const int t = threadIdx.x;
  const int CH = (NN + 1023) / 1024;  // 49
  const int base = t * CH;
  int s = 0;
  for (int i = 0; i < CH; ++i) { int idx = base + i; if (idx < NN) s += cnt[idx]; }
  part[t] = s;
  __syncthreads();
  for (int off = 1; off < 1024; off <<= 1) {
    int v = (t >= off) ? part[t - off] : 0;
    __syncthreads();
    part[t] += v;
    __syncthreads();
  }
  int run = (t == 0) ? 0 : part[t - 1];
  for (int i = 0; i < CH; ++i) {
    int idx = base + i;
    if (idx < NN) { rowptr[idx] = run; cursor[idx] = run; run += cnt[idx]; }
  }
  if (t == 1023) rowptr[NN] = part[1023];
}

__global__ void fill_kernel(const int* __restrict__ src, const int* __restrict__ dst,
                            int* __restrict__ cursor, int* __restrict__ esrc) {
  for (int e = blockIdx.x * blockDim.x + threadIdx.x; e < NE; e += gridDim.x * blockDim.x) {
    int p = atomicAdd(&cursor[dst[e]], 1);
    esrc[p] = src[e];
  }
}

// ------------------------------------------------------- proj: y = x @ W1_0
// (A x + x) @ W1 == A (x W1) + (x W1): project first so ALL gathers are 64-wide
__global__ __launch_bounds__(256) void proj_kernel(const float* __restrict__ x,
                                                   const float* __restrict__ w1,
                                                   float* __restrict__ y) {
  __shared__ float sW[128 * 64];
  __shared__ float sX[64 * 128];
  const int t = threadIdx.x, c = t & 63, rg = t >> 6;
  for (int i = t; i < 128 * 64; i += 256) sW[i] = w1[i];
  const int ntiles = (NN + 63) / 64;
  for (int tile = blockIdx.x; tile < ntiles; tile += gridDim.x) {
    const int r0 = tile * 64, nv = min(64, NN - r0);
    __syncthreads();  // protect sX overwrite (and first-use of sW)
    for (int i = t; i < nv * 32; i += 256)
      ((float4*)sX)[i] = ((const float4*)(x + (size_t)r0 * 128))[i];
    __syncthreads();
    float acc[16];
#pragma unroll
    for (int i = 0; i < 16; ++i) acc[i] = 0.f;
    for (int k = 0; k < 128; k += 4) {
      const float w0 = sW[(k + 0) * 64 + c], w1v = sW[(k + 1) * 64 + c],
                  w2v = sW[(k + 2) * 64 + c], w3v = sW[(k + 3) * 64 + c];
#pragma unroll
      for (int i = 0; i < 16; ++i) {
        const float4 xv = *(const float4*)&sX[(rg * 16 + i) * 128 + k];
        acc[i] = fmaf(xv.x, w0, acc[i]);
        acc[i] = fmaf(xv.y, w1v, acc[i]);
        acc[i] = fmaf(xv.z, w2v, acc[i]);
        acc[i] = fmaf(xv.w, w3v, acc[i]);
      }
    }
#pragma unroll
    for (int i = 0; i < 16; ++i) {
      const int r = rg * 16 + i;
      if (r < nv) y[(size_t)(r0 + r) * 64 + c] = acc[i];
    }
  }
}

// ---------------------------------------------------- gather: z = A h + h
// wave per row; quarter-wave (16 lanes x float4) per edge, 4 edges at a time,
// unrolled x2 -> 8 row-loads in flight per wave; no LDS -> max occupancy.
__global__ __launch_bounds__(256, 8) void agg_kernel(const float* __restrict__ h,
                                                     const int* __restrict__ rowptr,
                                                     const int* __restrict__ esrc,
                                                     float* __restrict__ z) {
  const int ln = threadIdx.x & 63, wv = threadIdx.x >> 6;
  const int q = ln >> 4, i = ln & 15;
  const int row = blockIdx.x * 4 + wv;
  if (row >= NN) return;
  const int beg = rowptr[row], end = rowptr[row + 1];
  float4 acc = {0.f, 0.f, 0.f, 0.f};
  if (q == 0) acc = *(const float4*)&h[(size_t)row * 64 + i * 4];  // self term
  int e = beg + q;
  for (; e + 4 < end; e += 8) {
    const int s0 = esrc[e];
    const int s1 = esrc[e + 4];
    const float4 v0 = *(const float4*)&h[(size_t)s0 * 64 + i * 4];
    const float4 v1 = *(const float4*)&h[(size_t)s1 * 64 + i * 4];
    acc.x += v0.x + v1.x;
    acc.y += v0.y + v1.y;
    acc.z += v0.z + v1.z;
    acc.w += v0.w + v1.w;
  }
  for (; e < end; e += 4) {
    const int s = esrc[e];
    const float4 v = *(const float4*)&h[(size_t)s * 64 + i * 4];
    acc.x += v.x; acc.y += v.y; acc.z += v.z; acc.w += v.w;
  }
#pragma unroll
  for (int off = 16; off < 64; off <<= 1) {
    acc.x += __shfl_xor(acc.x, off);
    acc.y += __shfl_xor(acc.y, off);
    acc.z += __shfl_xor(acc.z, off);
    acc.w += __shfl_xor(acc.w, off);
  }
  if (q == 0) *(float4*)&z[(size_t)row * 64 + i * 4] = acc;
}

// -------------------------------------------------- MLP (+JK chunk) per layer
// HASW1: h1 = relu(z@W1+b1); else (layer 0, pre-projected): h1 = relu(z+b1)
// h = relu(h1@W2+b2) -> hout;  hjk (+)= h@WJ  (init with jk_b when FIRST)
template <bool HASW1, bool FIRST>
__global__ __launch_bounds__(256) void mlp_kernel(
    const float* __restrict__ z, const float* __restrict__ w1,
    const float* __restrict__ b1, const float* __restrict__ w2,
    const float* __restrict__ b2, const float* __restrict__ wjk,
    const float* __restrict__ bjk, float* __restrict__ hout,
    float* __restrict__ hjk) {
  __shared__ float sW1[HASW1 ? 64 * 64 : 1];
  __shared__ float sW2[64 * 64];
  __shared__ float sWJ[64 * 64];
  __shared__ float sZ[64 * 64];  // reused: Z -> H1 -> H2
  const int t = threadIdx.x, c = t & 63, rg = t >> 6;
  if (HASW1)
    for (int i = t; i < 64 * 64; i += 256) sW1[i] = w1[i];
  for (int i = t; i < 64 * 64; i += 256) { sW2[i] = w2[i]; sWJ[i] = wjk[i]; }
  const float b1c = b1[c], b2c = b2[c], bjc = bjk[c];
  const int ntiles = (NN + 63) / 64;
  for (int tile = blockIdx.x; tile < ntiles; tile += gridDim.x) {
    const int r0 = tile * 64, nv = min(64, NN - r0);
    __syncthreads();  // protect sZ overwrite (and first-use of weights)
    if (HASW1) {
      for (int i = t; i < nv * 16; i += 256)
        ((float4*)sZ)[i] = ((const float4*)(z + (size_t)r0 * 64))[i];
    } else {
      // fuse h1 = relu(z + b1) into staging
      for (int i = t; i < nv * 16; i += 256) {
        float4 zv = ((const float4*)(z + (size_t)r0 * 64))[i];
        const float4 bv = *(const float4*)&b1[(i & 15) * 4];
        zv.x = fmaxf(zv.x + bv.x, 0.f);
        zv.y = fmaxf(zv.y + bv.y, 0.f);
        zv.z = fmaxf(zv.z + bv.z, 0.f);
        zv.w = fmaxf(zv.w + bv.w, 0.f);
        ((float4*)sZ)[i] = zv;
      }
    }
    __syncthreads();
    if (HASW1) {
      float acc[16];
#pragma unroll
      for (int i = 0; i < 16; ++i) acc[i] = b1c;
      for (int k = 0; k < 64; k += 4) {
        const float w0 = sW1[(k + 0) * 64 + c], w1v = sW1[(k + 1) * 64 + c],
                    w2v = sW1[(k + 2) * 64 + c], w3v = sW1[(k + 3) * 64 + c];
#pragma unroll
        for (int i = 0; i < 16; ++i) {
          const float4 zv = *(const float4*)&sZ[(rg * 16 + i) * 64 + k];
          acc[i] = fmaf(zv.x, w0, acc[i]);
          acc[i] = fmaf(zv.y, w1v, acc[i]);
          acc[i] = fmaf(zv.z, w2v, acc[i]);
          acc[i] = fmaf(zv.w, w3v, acc[i]);
        }
      }
      __syncthreads();
#pragma unroll
      for (int i = 0; i < 16; ++i) sZ[(rg * 16 + i) * 64 + c] = fmaxf(acc[i], 0.f);
      __syncthreads();
    }
    // matvec2: H2 = relu(H1 @ W2 + b2)
    float acc2[16];
#pragma unroll
    for (int i = 0; i < 16; ++i) acc2[i] = b2c;
    for (int k = 0; k < 64; k += 4) {
      const float w0 = sW2[(k + 0) * 64 + c], w1v = sW2[(k + 1) * 64 + c],
                  w2v = sW2[(k + 2) * 64 + c], w3v = sW2[(k + 3) * 64 + c];
#pragma unroll
      for (int i = 0; i < 16; ++i) {
        const float4 hv = *(const float4*)&sZ[(rg * 16 + i) * 64 + k];
        acc2[i] = fmaf(hv.x, w0, acc2[i]);
        acc2[i] = fmaf(hv.y, w1v, acc2[i]);
        acc2[i] = fmaf(hv.z, w2v, acc2[i]);
        acc2[i] = fmaf(hv.w, w3v, acc2[i]);
      }
    }
    __syncthreads();
#pragma unroll
    for (int i = 0; i < 16; ++i) {
      const int r = rg * 16 + i;
      const float hval = fmaxf(acc2[i], 0.f);
      sZ[r * 64 + c] = hval;
      if (r < nv) hout[(size_t)(r0 + r) * 64 + c] = hval;
    }
    __syncthreads();
    // matvec3: hjk chunk
    float accj[16];
#pragma unroll
    for (int i = 0; i < 16; ++i) accj[i] = FIRST ? bjc : 0.f;
    for (int k = 0; k < 64; k += 4) {
      const float w0 = sWJ[(k + 0) * 64 + c], w1v = sWJ[(k + 1) * 64 + c],
                  w2v = sWJ[(k + 2) * 64 + c], w3v = sWJ[(k + 3) * 64 + c];
#pragma unroll
      for (int i = 0; i < 16; ++i) {
        const float4 hv = *(const float4*)&sZ[(rg * 16 + i) * 64 + k];
        accj[i] = fmaf(hv.x, w0, accj[i]);
        accj[i] = fmaf(hv.y, w1v, accj[i]);
        accj[i] = fmaf(hv.z, w2v, accj[i]);
        accj[i] = fmaf(hv.w, w3v, accj[i]);
      }
    }
#pragma unroll
    for (int i = 0; i < 16; ++i) {
      const int r = rg * 16 + i;
      if (r < nv) {
        const size_t o = (size_t)(r0 + r) * 64 + c;
        hjk[o] = FIRST ? accj[i] : hjk[o] + accj[i];
      }
    }
  }
}

// ------------------------------------------- add-pool (batch is sorted!)
// wave owns a contiguous node chunk; register run-length accumulate per graph
__global__ __launch_bounds__(256) void pool_kernel(const float* __restrict__ hjk,
                                                   const int* __restrict__ batch,
                                                   float* __restrict__ g) {
  const int wgid = blockIdx.x * 4 + (threadIdx.x >> 6);
  const int c = threadIdx.x & 63;
  const int W = gridDim.x * 4;
  const int chunk = (NN + W - 1) / W;
  const int n0 = wgid * chunk, n1 = min(n0 + chunk, NN);
  if (n0 >= n1) return;
  float acc = 0.f;
  int cur = batch[n0];
  for (int n = n0; n < n1; ++n) {
    const int b = batch[n];
    const float v = hjk[(size_t)n * 64 + c];
    if (b != cur) { atomicAdd(&g[cur * 64 + c], acc); acc = 0.f; cur = b; }
    acc += v;
  }
  atomicAdd(&g[cur * 64 + c], acc);
}

// ------------------------------------------------------------- classifier
__global__ __launch_bounds__(256) void classifier_kernel(
    const float* __restrict__ g, const float* __restrict__ w1,
    const float* __restrict__ b1, const float* __restrict__ gamma,
    const float* __restrict__ beta, const float* __restrict__ w2,
    const float* __restrict__ b2, float* __restrict__ out) {
  __shared__ float sG[NG * 64];
  __shared__ float sT[NG * 64];
  __shared__ float sW1[64 * 64];
  __shared__ float sW2[64 * OUTC];
  __shared__ float sMu[64], sRs[64];
  const int t = threadIdx.x;
  for (int i = t; i < 64 * 64; i += 256) sW1[i] = w1[i];
  for (int i = t; i < 64 * OUTC; i += 256) sW2[i] = w2[i];
  for (int i = t; i < NG * 64; i += 256) sG[i] = g[i];
  __syncthreads();
  for (int idx = t; idx < NG * 64; idx += 256) {
    const int gi = idx >> 6, c = idx & 63;
    float a = b1[c];
    for (int k = 0; k < 64; ++k) a += sG[gi * 64 + k] * sW1[k * 64 + c];
    sT[idx] = a;
  }
  __syncthreads();
  if (t < 64) {
    float s = 0.f;
    for (int gi = 0; gi < NG; ++gi) s += sT[gi * 64 + t];
    const float mu = s / NG;
    float v = 0.f;
    for (int gi = 0; gi < NG; ++gi) { const float d = sT[gi * 64 + t] - mu; v += d * d; }
    v /= NG;
    sMu[t] = mu;
    sRs[t] = rsqrtf(v + 1e-5f);
  }
  __syncthreads();
  for (int idx = t; idx < NG * 64; idx += 256) {
    const int c = idx & 63;
    sT[idx] = fmaxf((sT[idx] - sMu[c]) * sRs[c] * gamma[c] + beta[c], 0.f);
  }
  __syncthreads();
  for (int idx = t; idx < NG * OUTC; idx += 256) {
    const int gi = idx / OUTC, o = idx % OUTC;
    float a = b2[o];
    for (int k = 0; k < 64; ++k) a += sT[gi * 64 + k] * sW2[k * OUTC + o];
    out[idx] = a;
  }
}

// ---------------------------------------------------------------- launch
extern "C" void kernel_launch(void* const* d_in, const int* in_sizes, int n_in,
                              void* d_out, int out_size, void* d_ws, size_t ws_size,
                              hipStream_t stream) {
  const float* x     = (const float*)d_in[0];
  const int*   ei    = (const int*)d_in[1];
  const int*   batch = (const int*)d_in[2];
  const float* w1_0  = (const float*)d_in[3];
  const float* b1_0  = (const float*)d_in[4];
  const float* w2_0  = (const float*)d_in[5];
  const float* b2_0  = (const float*)d_in[6];
  const float* w1_r  = (const float*)d_in[7];
  const float* b1_r  = (const float*)d_in[8];
  const float* w2_r  = (const float*)d_in[9];
  const float* b2_r  = (const float*)d_in[10];
  const float* jk_w  = (const float*)d_in[11];
  const float* jk_b  = (const float*)d_in[12];
  const float* cw1   = (const float*)d_in[13];
  const float* cb1   = (const float*)d_in[14];
  const float* bng   = (const float*)d_in[15];
  const float* bnb   = (const float*)d_in[16];
  const float* cw2   = (const float*)d_in[17];
  const float* cb2   = (const float*)d_in[18];
  float* out = (float*)d_out;

  char* base = (char*)d_ws;
  size_t o = 0;
  auto take = [&](size_t n) { char* p = base + o; o = (o + n + 255) & ~(size_t)255; return p; };
  int*   cnt    = (int*)take((size_t)NN * 4);
  int*   rowptr = (int*)take((size_t)(NN + 1) * 4);
  int*   cursor = (int*)take((size_t)NN * 4);
  int*   esrc   = (int*)take((size_t)NE * 4);
  float* hA     = (float*)take((size_t)NN * 64 * 4);
  float* hB     = (float*)take((size_t)NN * 64 * 4);
  float* z      = (float*)take((size_t)NN * 64 * 4);
  float* hjk    = (float*)take((size_t)NN * 64 * 4);
  float* g      = (float*)take((size_t)NG * 64 * 4);
  (void)ws_size; (void)in_sizes; (void)n_in; (void)out_size;

  hipMemsetAsync(cnt, 0, (size_t)NN * 4, stream);
  hipMemsetAsync(g, 0, (size_t)NG * 64 * 4, stream);

  const int* src = ei;
  const int* dst = ei + NE;
  count_kernel<<<1024, 256, 0, stream>>>(dst, cnt);
  scan_kernel<<<1, 1024, 0, stream>>>(cnt, rowptr, cursor);
  fill_kernel<<<1024, 256, 0, stream>>>(src, dst, cursor, esrc);

  // layer 0 (pre-projected): y = x@W1_0 (into hB), z = A y + y, MLP w/o W1
  proj_kernel<<<512, 256, 0, stream>>>(x, w1_0, hB);
  agg_kernel<<<(NN + 3) / 4, 256, 0, stream>>>(hB, rowptr, esrc, z);
  mlp_kernel<false, true><<<512, 256, 0, stream>>>(z, nullptr, b1_0, w2_0, b2_0,
                                                   jk_w, jk_b, hA, hjk);
  const float* hin = hA;
  float* hout = hB;
  for (int l = 1; l < 5; ++l) {
    agg_kernel<<<(NN + 3) / 4, 256, 0, stream>>>(hin, rowptr, esrc, z);
    mlp_kernel<true, false><<<512, 256, 0, stream>>>(
        z, w1_r + (size_t)(l - 1) * 64 * 64, b1_r + (size_t)(l - 1) * 64,
        w2_r + (size_t)(l - 1) * 64 * 64, b2_r + (size_t)(l - 1) * 64,
        jk_w + (size_t)l * 64 * 64, jk_b, hout, hjk);
    float* tmp = (float*)hin;
    hin = hout;
    hout = tmp;
  }

  pool_kernel<<<256, 256, 0, stream>>>(hjk, batch, g);
  classifier_kernel<<<1, 256, 0, stream>>>(g, cw1, cb1, bng, bnb, cw2, cb2, out);
}

// Round 3
// 617.900 us; speedup vs baseline: 2.4218x; 1.1589x over previous
//
#include <hip/hip_runtime.h>

#define NN 50000
#define NE 800000
#define NG 128
#define OUTC 10
#define SCAN_NB ((NN + 255) / 256)  // 196

// ---------------------------------------------------------------- CSR build
__global__ void count_kernel(const int* __restrict__ dst, int* __restrict__ cnt) {
  for (int e = blockIdx.x * blockDim.x + threadIdx.x; e < NE; e += gridDim.x * blockDim.x)
    atomicAdd(&cnt[dst[e]], 1);
}

// stage 1: per-block chunk sums
__global__ __launch_bounds__(256) void partial_kernel(const int* __restrict__ cnt,
                                                      int* __restrict__ part) {
  __shared__ int red[256];
  const int t = threadIdx.x;
  const int idx = blockIdx.x * 256 + t;
  red[t] = (idx < NN) ? cnt[idx] : 0;
  __syncthreads();
#pragma unroll
  for (int off = 128; off > 0; off >>= 1) {
    if (t < off) red[t] += red[t + off];
    __syncthreads();
  }
  if (t == 0) part[blockIdx.x] = red[0];
}

// stage 2: exclusive scan of the partials (1 tiny block)
__global__ __launch_bounds__(256) void scanpart_kernel(int* __restrict__ part) {
  __shared__ int s[256];
  const int t = threadIdx.x;
  s[t] = (t < SCAN_NB) ? part[t] : 0;
  __syncthreads();
#pragma unroll
  for (int off = 1; off < 256; off <<= 1) {
    const int v = (t >= off) ? s[t - off] : 0;
    __syncthreads();
    s[t] += v;
    __syncthreads();
  }
  if (t < SCAN_NB) part[t] = (t == 0) ? 0 : s[t - 1];
}

// stage 3: block-local exclusive scan + partial offset -> rowptr, cursor
__global__ __launch_bounds__(256) void scatter_scan_kernel(const int* __restrict__ cnt,
                                                           const int* __restrict__ part,
                                                           int* __restrict__ rowptr,
                                                           int* __restrict__ cursor) {
  __shared__ int s[256];
  const int t = threadIdx.x;
  const int idx = blockIdx.x * 256 + t;
  s[t] = (idx < NN) ? cnt[idx] : 0;
  __syncthreads();
#pragma unroll
  for (int off = 1; off < 256; off <<= 1) {
    const int v = (t >= off) ? s[t - off] : 0;
    __syncthreads();
    s[t] += v;
    __syncthreads();
  }
  const int excl = part[blockIdx.x] + ((t == 0) ? 0 : s[t - 1]);
  if (idx < NN) { rowptr[idx] = excl; cursor[idx] = excl; }
  if (idx == 0) rowptr[NN] = NE;  // total edge count is static
}

__global__ void fill_kernel(const int* __restrict__ src, const int* __restrict__ dst,
                            int* __restrict__ cursor, int* __restrict__ esrc) {
  for (int e = blockIdx.x * blockDim.x + threadIdx.x; e < NE; e += gridDim.x * blockDim.x) {
    int p = atomicAdd(&cursor[dst[e]], 1);
    esrc[p] = src[e];
  }
}

// ------------------------------------------------------- proj: y = x @ W1_0
// (A x + x) @ W1 == A (x W1) + (x W1): project first so ALL gathers are 64-wide
__global__ __launch_bounds__(256) void proj_kernel(const float* __restrict__ x,
                                                   const float* __restrict__ w1,
                                                   float* __restrict__ y) {
  __shared__ float sW[128 * 64];
  __shared__ float sX[64 * 128];
  const int t = threadIdx.x, c = t & 63, rg = t >> 6;
  for (int i = t; i < 128 * 64; i += 256) sW[i] = w1[i];
  const int ntiles = (NN + 63) / 64;
  for (int tile = blockIdx.x; tile < ntiles; tile += gridDim.x) {
    const int r0 = tile * 64, nv = min(64, NN - r0);
    __syncthreads();  // protect sX overwrite (and first-use of sW)
    for (int i = t; i < nv * 32; i += 256)
      ((float4*)sX)[i] = ((const float4*)(x + (size_t)r0 * 128))[i];
    __syncthreads();
    float acc[16];
#pragma unroll
    for (int i = 0; i < 16; ++i) acc[i] = 0.f;
    for (int k = 0; k < 128; k += 4) {
      const float w0 = sW[(k + 0) * 64 + c], w1v = sW[(k + 1) * 64 + c],
                  w2v = sW[(k + 2) * 64 + c], w3v = sW[(k + 3) * 64 + c];
#pragma unroll
      for (int i = 0; i < 16; ++i) {
        const float4 xv = *(const float4*)&sX[(rg * 16 + i) * 128 + k];
        acc[i] = fmaf(xv.x, w0, acc[i]);
        acc[i] = fmaf(xv.y, w1v, acc[i]);
        acc[i] = fmaf(xv.z, w2v, acc[i]);
        acc[i] = fmaf(xv.w, w3v, acc[i]);
      }
    }
#pragma unroll
    for (int i = 0; i < 16; ++i) {
      const int r = rg * 16 + i;
      if (r < nv) y[(size_t)(r0 + r) * 64 + c] = acc[i];
    }
  }
}

// ---------------------------------------------------- gather: z = A h + h
// wave per row; quarter-wave (16 lanes x float4) per edge, 4 edges/iter,
// unrolled x4 -> 16 row-loads in flight per wave; no LDS -> max occupancy.
__global__ __launch_bounds__(256, 8) void agg_kernel(const float* __restrict__ h,
                                                     const int* __restrict__ rowptr,
                                                     const int* __restrict__ esrc,
                                                     float* __restrict__ z) {
  const int ln = threadIdx.x & 63, wv = threadIdx.x >> 6;
  const int q = ln >> 4, i = ln & 15;
  const int row = blockIdx.x * 4 + wv;
  if (row >= NN) return;
  const int beg = rowptr[row], end = rowptr[row + 1];
  float4 acc = {0.f, 0.f, 0.f, 0.f};
  if (q == 0) acc = *(const float4*)&h[(size_t)row * 64 + i * 4];  // self term
  int e = beg + q;
  for (; e + 12 < end; e += 16) {
    const int s0 = esrc[e];
    const int s1 = esrc[e + 4];
    const int s2 = esrc[e + 8];
    const int s3 = esrc[e + 12];
    const float4 v0 = *(const float4*)&h[(size_t)s0 * 64 + i * 4];
    const float4 v1 = *(const float4*)&h[(size_t)s1 * 64 + i * 4];
    const float4 v2 = *(const float4*)&h[(size_t)s2 * 64 + i * 4];
    const float4 v3 = *(const float4*)&h[(size_t)s3 * 64 + i * 4];
    acc.x += (v0.x + v1.x) + (v2.x + v3.x);
    acc.y += (v0.y + v1.y) + (v2.y + v3.y);
    acc.z += (v0.z + v1.z) + (v2.z + v3.z);
    acc.w += (v0.w + v1.w) + (v2.w + v3.w);
  }
  for (; e + 4 < end; e += 8) {
    const int s0 = esrc[e];
    const int s1 = esrc[e + 4];
    const float4 v0 = *(const float4*)&h[(size_t)s0 * 64 + i * 4];
    const float4 v1 = *(const float4*)&h[(size_t)s1 * 64 + i * 4];
    acc.x += v0.x + v1.x;
    acc.y += v0.y + v1.y;
    acc.z += v0.z + v1.z;
    acc.w += v0.w + v1.w;
  }
  for (; e < end; e += 4) {
    const int s = esrc[e];
    const float4 v = *(const float4*)&h[(size_t)s * 64 + i * 4];
    acc.x += v.x; acc.y += v.y; acc.z += v.z; acc.w += v.w;
  }
#pragma unroll
  for (int off = 16; off < 64; off <<= 1) {
    acc.x += __shfl_xor(acc.x, off);
    acc.y += __shfl_xor(acc.y, off);
    acc.z += __shfl_xor(acc.z, off);
    acc.w += __shfl_xor(acc.w, off);
  }
  if (q == 0) *(float4*)&z[(size_t)row * 64 + i * 4] = acc;
}

// -------------------------------------------------- MLP (+JK chunk) per layer
// HASW1: h1 = relu(z@W1+b1); else (layer 0, pre-projected): h1 = relu(z+b1)
// h = relu(h1@W2+b2) -> hout;  hjk (+)= h@WJ  (init with jk_b when FIRST)
template <bool HASW1, bool FIRST>
__global__ __launch_bounds__(256) void mlp_kernel(
    const float* __restrict__ z, const float* __restrict__ w1,
    const float* __restrict__ b1, const float* __restrict__ w2,
    const float* __restrict__ b2, const float* __restrict__ wjk,
    const float* __restrict__ bjk, float* __restrict__ hout,
    float* __restrict__ hjk) {
  __shared__ float sW1[HASW1 ? 64 * 64 : 1];
  __shared__ float sW2[64 * 64];
  __shared__ float sWJ[64 * 64];
  __shared__ float sZ[64 * 64];  // reused: Z -> H1 -> H2
  const int t = threadIdx.x, c = t & 63, rg = t >> 6;
  if (HASW1)
    for (int i = t; i < 64 * 64; i += 256) sW1[i] = w1[i];
  for (int i = t; i < 64 * 64; i += 256) { sW2[i] = w2[i]; sWJ[i] = wjk[i]; }
  const float b1c = b1[c], b2c = b2[c], bjc = bjk[c];
  const int ntiles = (NN + 63) / 64;
  for (int tile = blockIdx.x; tile < ntiles; tile += gridDim.x) {
    const int r0 = tile * 64, nv = min(64, NN - r0);
    __syncthreads();  // protect sZ overwrite (and first-use of weights)
    if (HASW1) {
      for (int i = t; i < nv * 16; i += 256)
        ((float4*)sZ)[i] = ((const float4*)(z + (size_t)r0 * 64))[i];
    } else {
      // fuse h1 = relu(z + b1) into staging
      for (int i = t; i < nv * 16; i += 256) {
        float4 zv = ((const float4*)(z + (size_t)r0 * 64))[i];
        const float4 bv = *(const float4*)&b1[(i & 15) * 4];
        zv.x = fmaxf(zv.x + bv.x, 0.f);
        zv.y = fmaxf(zv.y + bv.y, 0.f);
        zv.z = fmaxf(zv.z + bv.z, 0.f);
        zv.w = fmaxf(zv.w + bv.w, 0.f);
        ((float4*)sZ)[i] = zv;
      }
    }
    __syncthreads();
    if (HASW1) {
      float acc[16];
#pragma unroll
      for (int i = 0; i < 16; ++i) acc[i] = b1c;
      for (int k = 0; k < 64; k += 4) {
        const float w0 = sW1[(k + 0) * 64 + c], w1v = sW1[(k + 1) * 64 + c],
                    w2v = sW1[(k + 2) * 64 + c], w3v = sW1[(k + 3) * 64 + c];
#pragma unroll
        for (int i = 0; i < 16; ++i) {
          const float4 zv = *(const float4*)&sZ[(rg * 16 + i) * 64 + k];
          acc[i] = fmaf(zv.x, w0, acc[i]);
          acc[i] = fmaf(zv.y, w1v, acc[i]);
          acc[i] = fmaf(zv.z, w2v, acc[i]);
          acc[i] = fmaf(zv.w, w3v, acc[i]);
        }
      }
      __syncthreads();
#pragma unroll
      for (int i = 0; i < 16; ++i) sZ[(rg * 16 + i) * 64 + c] = fmaxf(acc[i], 0.f);
      __syncthreads();
    }
    // matvec2: H2 = relu(H1 @ W2 + b2)
    float acc2[16];
#pragma unroll
    for (int i = 0; i < 16; ++i) acc2[i] = b2c;
    for (int k = 0; k < 64; k += 4) {
      const float w0 = sW2[(k + 0) * 64 + c], w1v = sW2[(k + 1) * 64 + c],
                  w2v = sW2[(k + 2) * 64 + c], w3v = sW2[(k + 3) * 64 + c];
#pragma unroll
      for (int i = 0; i < 16; ++i) {
        const float4 hv = *(const float4*)&sZ[(rg * 16 + i) * 64 + k];
        acc2[i] = fmaf(hv.x, w0, acc2[i]);
        acc2[i] = fmaf(hv.y, w1v, acc2[i]);
        acc2[i] = fmaf(hv.z, w2v, acc2[i]);
        acc2[i] = fmaf(hv.w, w3v, acc2[i]);
      }
    }
    __syncthreads();
#pragma unroll
    for (int i = 0; i < 16; ++i) {
      const int r = rg * 16 + i;
      const float hval = fmaxf(acc2[i], 0.f);
      sZ[r * 64 + c] = hval;
      if (r < nv) hout[(size_t)(r0 + r) * 64 + c] = hval;
    }
    __syncthreads();
    // matvec3: hjk chunk
    float accj[16];
#pragma unroll
    for (int i = 0; i < 16; ++i) accj[i] = FIRST ? bjc : 0.f;
    for (int k = 0; k < 64; k += 4) {
      const float w0 = sWJ[(k + 0) * 64 + c], w1v = sWJ[(k + 1) * 64 + c],
                  w2v = sWJ[(k + 2) * 64 + c], w3v = sWJ[(k + 3) * 64 + c];
#pragma unroll
      for (int i = 0; i < 16; ++i) {
        const float4 hv = *(const float4*)&sZ[(rg * 16 + i) * 64 + k];
        accj[i] = fmaf(hv.x, w0, accj[i]);
        accj[i] = fmaf(hv.y, w1v, accj[i]);
        accj[i] = fmaf(hv.z, w2v, accj[i]);
        accj[i] = fmaf(hv.w, w3v, accj[i]);
      }
    }
#pragma unroll
    for (int i = 0; i < 16; ++i) {
      const int r = rg * 16 + i;
      if (r < nv) {
        const size_t o = (size_t)(r0 + r) * 64 + c;
        hjk[o] = FIRST ? accj[i] : hjk[o] + accj[i];
      }
    }
  }
}

// ------------------------------------------- add-pool (batch is sorted!)
// wave owns a contiguous node chunk; register run-length accumulate per graph
__global__ __launch_bounds__(256) void pool_kernel(const float* __restrict__ hjk,
                                                   const int* __restrict__ batch,
                                                   float* __restrict__ g) {
  const int wgid = blockIdx.x * 4 + (threadIdx.x >> 6);
  const int c = threadIdx.x & 63;
  const int W = gridDim.x * 4;
  const int chunk = (NN + W - 1) / W;
  const int n0 = wgid * chunk, n1 = min(n0 + chunk, NN);
  if (n0 >= n1) return;
  float acc = 0.f;
  int cur = batch[n0];
  for (int n = n0; n < n1; ++n) {
    const int b = batch[n];
    const float v = hjk[(size_t)n * 64 + c];
    if (b != cur) { atomicAdd(&g[cur * 64 + c], acc); acc = 0.f; cur = b; }
    acc += v;
  }
  atomicAdd(&g[cur * 64 + c], acc);
}

// ------------------------------------------------------------- classifier
__global__ __launch_bounds__(256) void classifier_kernel(
    const float* __restrict__ g, const float* __restrict__ w1,
    const float* __restrict__ b1, const float* __restrict__ gamma,
    const float* __restrict__ beta, const float* __restrict__ w2,
    const float* __restrict__ b2, float* __restrict__ out) {
  __shared__ float sG[NG * 64];
  __shared__ float sT[NG * 64];
  __shared__ float sW1[64 * 64];
  __shared__ float sW2[64 * OUTC];
  __shared__ float sMu[64], sRs[64];
  const int t = threadIdx.x;
  for (int i = t; i < 64 * 64; i += 256) sW1[i] = w1[i];
  for (int i = t; i < 64 * OUTC; i += 256) sW2[i] = w2[i];
  for (int i = t; i < NG * 64; i += 256) sG[i] = g[i];
  __syncthreads();
  for (int idx = t; idx < NG * 64; idx += 256) {
    const int gi = idx >> 6, c = idx & 63;
    float a = b1[c];
    for (int k = 0; k < 64; ++k) a += sG[gi * 64 + k] * sW1[k * 64 + c];
    sT[idx] = a;
  }
  __syncthreads();
  if (t < 64) {
    float s = 0.f;
    for (int gi = 0; gi < NG; ++gi) s += sT[gi * 64 + t];
    const float mu = s / NG;
    float v = 0.f;
    for (int gi = 0; gi < NG; ++gi) { const float d = sT[gi * 64 + t] - mu; v += d * d; }
    v /= NG;
    sMu[t] = mu;
    sRs[t] = rsqrtf(v + 1e-5f);
  }
  __syncthreads();
  for (int idx = t; idx < NG * 64; idx += 256) {
    const int c = idx & 63;
    sT[idx] = fmaxf((sT[idx] - sMu[c]) * sRs[c] * gamma[c] + beta[c], 0.f);
  }
  __syncthreads();
  for (int idx = t; idx < NG * OUTC; idx += 256) {
    const int gi = idx / OUTC, o = idx % OUTC;
    float a = b2[o];
    for (int k = 0; k < 64; ++k) a += sT[gi * 64 + k] * sW2[k * OUTC + o];
    out[idx] = a;
  }
}

// ---------------------------------------------------------------- launch
extern "C" void kernel_launch(void* const* d_in, const int* in_sizes, int n_in,
                              void* d_out, int out_size, void* d_ws, size_t ws_size,
                              hipStream_t stream) {
  const float* x     = (const float*)d_in[0];
  const int*   ei    = (const int*)d_in[1];
  const int*   batch = (const int*)d_in[2];
  const float* w1_0  = (const float*)d_in[3];
  const float* b1_0  = (const float*)d_in[4];
  const float* w2_0  = (const float*)d_in[5];
  const float* b2_0  = (const float*)d_in[6];
  const float* w1_r  = (const float*)d_in[7];
  const float* b1_r  = (const float*)d_in[8];
  const float* w2_r  = (const float*)d_in[9];
  const float* b2_r  = (const float*)d_in[10];
  const float* jk_w  = (const float*)d_in[11];
  const float* jk_b  = (const float*)d_in[12];
  const float* cw1   = (const float*)d_in[13];
  const float* cb1   = (const float*)d_in[14];
  const float* bng   = (const float*)d_in[15];
  const float* bnb   = (const float*)d_in[16];
  const float* cw2   = (const float*)d_in[17];
  const float* cb2   = (const float*)d_in[18];
  float* out = (float*)d_out;

  char* base = (char*)d_ws;
  size_t o = 0;
  auto take = [&](size_t n) { char* p = base + o; o = (o + n + 255) & ~(size_t)255; return p; };
  int*   cnt    = (int*)take((size_t)NN * 4);
  int*   rowptr = (int*)take((size_t)(NN + 1) * 4);
  int*   cursor = (int*)take((size_t)NN * 4);
  int*   part   = (int*)take((size_t)SCAN_NB * 4);
  int*   esrc   = (int*)take((size_t)NE * 4);
  float* hA     = (float*)take((size_t)NN * 64 * 4);
  float* hB     = (float*)take((size_t)NN * 64 * 4);
  float* z      = (float*)take((size_t)NN * 64 * 4);
  float* hjk    = (float*)take((size_t)NN * 64 * 4);
  float* g      = (float*)take((size_t)NG * 64 * 4);
  (void)ws_size; (void)in_sizes; (void)n_in; (void)out_size;

  hipMemsetAsync(cnt, 0, (size_t)NN * 4, stream);
  hipMemsetAsync(g, 0, (size_t)NG * 64 * 4, stream);

  const int* src = ei;
  const int* dst = ei + NE;
  count_kernel<<<1024, 256, 0, stream>>>(dst, cnt);
  partial_kernel<<<SCAN_NB, 256, 0, stream>>>(cnt, part);
  scanpart_kernel<<<1, 256, 0, stream>>>(part);
  scatter_scan_kernel<<<SCAN_NB, 256, 0, stream>>>(cnt, part, rowptr, cursor);
  fill_kernel<<<1024, 256, 0, stream>>>(src, dst, cursor, esrc);

  // layer 0 (pre-projected): y = x@W1_0 (into hB), z = A y + y, MLP w/o W1
  proj_kernel<<<512, 256, 0, stream>>>(x, w1_0, hB);
  agg_kernel<<<(NN + 3) / 4, 256, 0, stream>>>(hB, rowptr, esrc, z);
  mlp_kernel<false, true><<<512, 256, 0, stream>>>(z, nullptr, b1_0, w2_0, b2_0,
                                                   jk_w, jk_b, hA, hjk);
  const float* hin = hA;
  float* hout = hB;
  for (int l = 1; l < 5; ++l) {
    agg_kernel<<<(NN + 3) / 4, 256, 0, stream>>>(hin, rowptr, esrc, z);
    mlp_kernel<true, false><<<512, 256, 0, stream>>>(
        z, w1_r + (size_t)(l - 1) * 64 * 64, b1_r + (size_t)(l - 1) * 64,
        w2_r + (size_t)(l - 1) * 64 * 64, b2_r + (size_t)(l - 1) * 64,
        jk_w + (size_t)l * 64 * 64, jk_b, hout, hjk);
    float* tmp = (float*)hin;
    hin = hout;
    hout = tmp;
  }

  pool_kernel<<<256, 256, 0, stream>>>(hjk, batch, g);
  classifier_kernel<<<1, 256, 0, stream>>>(g, cw1, cb1, bng, bnb, cw2, cb2, out);
}